// Round 6
// baseline (316.033 us; speedup 1.0000x reference)
//
#include <hip/hip_runtime.h>

#define BN_EPS 1e-3f

typedef __attribute__((ext_vector_type(8))) short bf16x8;
typedef __attribute__((ext_vector_type(4))) short short4v;
typedef __attribute__((ext_vector_type(4))) float f32x4;

__device__ __forceinline__ short f2bf(float f) {
    union { float f; unsigned u; } a; a.f = f;
    unsigned r = a.u + 0x7fffu + ((a.u >> 16) & 1u);
    return (short)(r >> 16);
}
__device__ __forceinline__ float bf2f(short s) {
    union { unsigned u; float f; } a;
    a.u = ((unsigned)(unsigned short)s) << 16;
    return a.f;
}

// ---------------- K0: pre-split x into hi/lo LDS chunk images ----------------
// Xp[b][kc][plane][kg][f][e] ushort; chunk stride 8192 ushorts (16KB).
__global__ __launch_bounds__(512) void prep_x(const float* __restrict__ x,
                                              ushort* __restrict__ Xp) {
    const int b  = blockIdx.x >> 5;
    const int kc = blockIdx.x & 31;
    const int t  = threadIdx.x;
    const int f  = t & 127;
    const int kg = t >> 7;             // 0..3
    bf16x8 hi8, lo8;
    #pragma unroll
    for (int e = 0; e < 8; ++e) {
        const float val = x[((size_t)b * 1024 + kc * 32 + kg * 8 + e) * 128 + f];
        const short h = f2bf(val);
        hi8[e] = h; lo8[e] = f2bf(val - bf2f(h));
    }
    const size_t base = ((size_t)(b * 32 + kc)) * 8192 + (size_t)kg * 1024 + (size_t)f * 8;
    *reinterpret_cast<bf16x8*>(&Xp[base])        = hi8;
    *reinterpret_cast<bf16x8*>(&Xp[base + 4096]) = lo8;
}

// ---------------- K1: GIN aggregation as binary-MFMA GEMM (BM=64) ----------
// 512 blocks = 32 batches x 16 row-tiles; 8 waves (4 rowgrp x 2 colgrp).
__global__ __launch_bounds__(512, 4) void agg_mfma(
    const float* __restrict__ x, const float* __restrict__ a,
    const ushort* __restrict__ Xp, const float* __restrict__ epsp,
    float* __restrict__ h0) {
    __shared__ __align__(16) ushort Aab[4][64][8];        // 4 KB
    __shared__ __align__(16) ushort Xhl[2][4][128][8];    // 16 KB

    const int tid  = threadIdx.x;
    const int lane = tid & 63;
    const int wid  = tid >> 6;
    const int wr   = wid >> 1;       // row group: 16 rows
    const int wn   = wid & 1;        // col group: 64 f
    const int lr   = lane & 15;
    const int kg   = lane >> 4;
    const int b    = blockIdx.x >> 4;
    const int row0 = (blockIdx.x & 15) * 64;

    const float*  ab = a + ((size_t)b * 1024 + row0) * 1024;
    const ushort* xp = Xp + (size_t)b * 32 * 8192;

    const int ai  = tid >> 3;        // 0..63 (a row)
    const int akq = tid & 7;         // k quad (4 elems)

    f32x4 acc[4] = {};

    for (int kc = 0; kc < 32; ++kc) {
        f32x4 av = *reinterpret_cast<const f32x4*>(ab + (size_t)ai * 1024 + kc * 32 + akq * 4);
        const f32x4* xsrc = reinterpret_cast<const f32x4*>(xp + (size_t)kc * 8192);
        f32x4 xv0 = xsrc[tid];
        f32x4 xv1 = xsrc[512 + tid];
        __syncthreads();                  // prior chunk's frag reads done
        {
            short4v h4;
            h4[0] = f2bf(av.x); h4[1] = f2bf(av.y);       // exact: av in {0,1}
            h4[2] = f2bf(av.z); h4[3] = f2bf(av.w);
            *reinterpret_cast<short4v*>(&Aab[akq >> 1][ai][(akq & 1) * 4]) = h4;
        }
        f32x4* xdst = reinterpret_cast<f32x4*>(Xhl);
        xdst[tid] = xv0; xdst[512 + tid] = xv1;
        __syncthreads();

        bf16x8 af = *reinterpret_cast<bf16x8*>(&Aab[kg][wr * 16 + lr][0]);
        #pragma unroll
        for (int ni = 0; ni < 4; ++ni) {
            bf16x8 bh = *reinterpret_cast<bf16x8*>(&Xhl[0][kg][wn * 64 + ni * 16 + lr][0]);
            bf16x8 bl = *reinterpret_cast<bf16x8*>(&Xhl[1][kg][wn * 64 + ni * 16 + lr][0]);
            acc[ni] = __builtin_amdgcn_mfma_f32_16x16x32_bf16(af, bh, acc[ni], 0, 0, 0);
            acc[ni] = __builtin_amdgcn_mfma_f32_16x16x32_bf16(af, bl, acc[ni], 0, 0, 0);
        }
    }

    // epilogue: h0 = (1+eps)*x + agg
    const float ep1 = 1.0f + epsp[0];
    const float* xb = x + (size_t)b * 131072;
    #pragma unroll
    for (int ni = 0; ni < 4; ++ni) {
        const int col   = wn * 64 + ni * 16 + lr;
        const int rbase = row0 + wr * 16 + kg * 4;
        #pragma unroll
        for (int r = 0; r < 4; ++r) {
            const size_t off = (size_t)(rbase + r) * 128 + col;
            h0[(size_t)b * 131072 + off] = fmaf(ep1, xb[off], acc[ni][r]);
        }
    }
}

// ---------------- K2: W pre-split into LDS chunk images (verified) --------
__global__ __launch_bounds__(256) void prep_w(
    const float* __restrict__ w1, const float* __restrict__ w2,
    const float* __restrict__ w3, ushort* __restrict__ Wp) {
    const int k = blockIdx.x;      // 0..639 global k row
    const int c = threadIdx.x;     // 0..255
    const float* src; int kl, base;
    if (k < 128)      { src = w1; kl = k;       base = 0; }
    else if (k < 384) { src = w2; kl = k - 128; base = 65536; }
    else              { src = w3; kl = k - 384; base = 196608; }
    const float val = src[(size_t)kl * 256 + c];
    const short hi = f2bf(val);
    const short lo = f2bf(val - bf2f(hi));
    const int off = base + (kl >> 5) * 16384 + ((((kl >> 3) & 3) * 256 + c) * 8) + (kl & 7);
    Wp[off]        = (ushort)hi;
    Wp[off + 8192] = (ushort)lo;
}

// ---------------- K3: fused 3-layer MLP + max-pool (BM=64) -------------
// 512 blocks x 512 thr; 8 waves = 2 rowgrp(32 rows) x 4 colgrp(64 cols).
// acc[2][4] per wave; verified frag/staging layouts re-tiled: (kc&3)->(kc&1),
// participation wn==(kc>>1), ni=(kc&1)*2+j.
__global__ __launch_bounds__(512, 4) void fused_mlp(
    const float* __restrict__ h0, const ushort* __restrict__ Wp,
    const float* __restrict__ b1, const float* __restrict__ g1,
    const float* __restrict__ be1, const float* __restrict__ m1,
    const float* __restrict__ v1,
    const float* __restrict__ b2, const float* __restrict__ g2,
    const float* __restrict__ be2, const float* __restrict__ m2,
    const float* __restrict__ v2,
    const float* __restrict__ b3, const float* __restrict__ g3,
    const float* __restrict__ be3, const float* __restrict__ m3,
    const float* __restrict__ v3,
    float* __restrict__ pool) {
    __shared__ __align__(16) ushort Wb[2][4][256][8];    // 32KB [plane][kg][col][e]
    __shared__ __align__(16) ushort Ab[2][2][4][32][8];  // 8KB  [plane][wr][kg][row][e]

    const int tid  = threadIdx.x;
    const int lane = tid & 63;
    const int wid  = tid >> 6;
    const int wr   = wid >> 2;     // 0..1 (32 rows each)
    const int wn   = wid & 3;      // 0..3 (64 cols each)
    const int lr   = lane & 15;
    const int kg   = lane >> 4;
    const int row0 = blockIdx.x * 64;

    f32x4 acc1[2][4] = {};
    f32x4 acc2[2][4] = {};

    // ---- Layer 1: A from global h0 (fp32), K=128, 4 chunks ----
    const int arow = tid >> 3;          // 0..63
    const int akq  = tid & 7;           // k-quad (4 floats)
    const float* aptr = h0 + (size_t)(row0 + arow) * 128 + akq * 4;

    #pragma unroll
    for (int kc = 0; kc < 4; ++kc) {
        f32x4 av = *reinterpret_cast<const f32x4*>(aptr + kc * 32);
        const f32x4* wsrc = reinterpret_cast<const f32x4*>(Wp + kc * 16384);
        f32x4 wv0 = wsrc[tid], wv1 = wsrc[512 + tid];
        f32x4 wv2 = wsrc[1024 + tid], wv3 = wsrc[1536 + tid];
        __syncthreads();
        {
            float fx[4] = {av.x, av.y, av.z, av.w};
            short4v h4, l4;
            #pragma unroll
            for (int e = 0; e < 4; ++e) {
                const short h = f2bf(fx[e]);
                h4[e] = h; l4[e] = f2bf(fx[e] - bf2f(h));
            }
            *reinterpret_cast<short4v*>(&Ab[0][arow >> 5][akq >> 1][arow & 31][(akq & 1) * 4]) = h4;
            *reinterpret_cast<short4v*>(&Ab[1][arow >> 5][akq >> 1][arow & 31][(akq & 1) * 4]) = l4;
        }
        f32x4* wdst = reinterpret_cast<f32x4*>(Wb);
        wdst[tid] = wv0; wdst[512 + tid] = wv1;
        wdst[1024 + tid] = wv2; wdst[1536 + tid] = wv3;
        __syncthreads();

        bf16x8 ah0 = *reinterpret_cast<bf16x8*>(&Ab[0][wr][kg][lr][0]);
        bf16x8 al0 = *reinterpret_cast<bf16x8*>(&Ab[1][wr][kg][lr][0]);
        bf16x8 ah1 = *reinterpret_cast<bf16x8*>(&Ab[0][wr][kg][16 + lr][0]);
        bf16x8 al1 = *reinterpret_cast<bf16x8*>(&Ab[1][wr][kg][16 + lr][0]);
        #pragma unroll
        for (int ni = 0; ni < 4; ++ni) {
            bf16x8 bh = *reinterpret_cast<bf16x8*>(&Wb[0][kg][wn * 64 + ni * 16 + lr][0]);
            bf16x8 bl = *reinterpret_cast<bf16x8*>(&Wb[1][kg][wn * 64 + ni * 16 + lr][0]);
            acc1[0][ni] = __builtin_amdgcn_mfma_f32_16x16x32_bf16(ah0, bh, acc1[0][ni], 0, 0, 0);
            acc1[0][ni] = __builtin_amdgcn_mfma_f32_16x16x32_bf16(ah0, bl, acc1[0][ni], 0, 0, 0);
            acc1[0][ni] = __builtin_amdgcn_mfma_f32_16x16x32_bf16(al0, bh, acc1[0][ni], 0, 0, 0);
            acc1[1][ni] = __builtin_amdgcn_mfma_f32_16x16x32_bf16(ah1, bh, acc1[1][ni], 0, 0, 0);
            acc1[1][ni] = __builtin_amdgcn_mfma_f32_16x16x32_bf16(ah1, bl, acc1[1][ni], 0, 0, 0);
            acc1[1][ni] = __builtin_amdgcn_mfma_f32_16x16x32_bf16(al1, bh, acc1[1][ni], 0, 0, 0);
        }
    }

    // epilogue 1: bias+BN+relu in place
    #pragma unroll
    for (int ni = 0; ni < 4; ++ni) {
        const int c = wn * 64 + ni * 16 + lr;
        const float s  = g1[c] * rsqrtf(v1[c] + BN_EPS);
        const float tt = be1[c] - m1[c] * s;
        const float bb = b1[c];
        #pragma unroll
        for (int mi = 0; mi < 2; ++mi)
            #pragma unroll
            for (int r = 0; r < 4; ++r)
                acc1[mi][ni][r] = fmaxf(fmaf(acc1[mi][ni][r] + bb, s, tt), 0.f);
    }

    // ---- Layer 2: A from acc1 (regs), K=256, 8 chunks ----
    #pragma unroll
    for (int kc = 0; kc < 8; ++kc) {
        const f32x4* wsrc = reinterpret_cast<const f32x4*>(Wp + 65536 + kc * 16384);
        f32x4 wv0 = wsrc[tid], wv1 = wsrc[512 + tid];
        f32x4 wv2 = wsrc[1024 + tid], wv3 = wsrc[1536 + tid];
        __syncthreads();
        if (wn == (kc >> 1)) {           // this wave's cols cover chunk kc
            #pragma unroll
            for (int j = 0; j < 2; ++j) {
                const int ni  = (kc & 1) * 2 + j;
                const int kgw = j * 2 + (lr >> 3);
                const int e   = lr & 7;
                #pragma unroll
                for (int mi = 0; mi < 2; ++mi)
                    #pragma unroll
                    for (int r = 0; r < 4; ++r) {
                        const float val = acc1[mi][ni][r];
                        const short h = f2bf(val);
                        Ab[0][wr][kgw][mi * 16 + kg * 4 + r][e] = (ushort)h;
                        Ab[1][wr][kgw][mi * 16 + kg * 4 + r][e] = (ushort)f2bf(val - bf2f(h));
                    }
            }
        }
        f32x4* wdst = reinterpret_cast<f32x4*>(Wb);
        wdst[tid] = wv0; wdst[512 + tid] = wv1;
        wdst[1024 + tid] = wv2; wdst[1536 + tid] = wv3;
        __syncthreads();

        bf16x8 ah0 = *reinterpret_cast<bf16x8*>(&Ab[0][wr][kg][lr][0]);
        bf16x8 al0 = *reinterpret_cast<bf16x8*>(&Ab[1][wr][kg][lr][0]);
        bf16x8 ah1 = *reinterpret_cast<bf16x8*>(&Ab[0][wr][kg][16 + lr][0]);
        bf16x8 al1 = *reinterpret_cast<bf16x8*>(&Ab[1][wr][kg][16 + lr][0]);
        #pragma unroll
        for (int ni = 0; ni < 4; ++ni) {
            bf16x8 bh = *reinterpret_cast<bf16x8*>(&Wb[0][kg][wn * 64 + ni * 16 + lr][0]);
            bf16x8 bl = *reinterpret_cast<bf16x8*>(&Wb[1][kg][wn * 64 + ni * 16 + lr][0]);
            acc2[0][ni] = __builtin_amdgcn_mfma_f32_16x16x32_bf16(ah0, bh, acc2[0][ni], 0, 0, 0);
            acc2[0][ni] = __builtin_amdgcn_mfma_f32_16x16x32_bf16(ah0, bl, acc2[0][ni], 0, 0, 0);
            acc2[0][ni] = __builtin_amdgcn_mfma_f32_16x16x32_bf16(al0, bh, acc2[0][ni], 0, 0, 0);
            acc2[1][ni] = __builtin_amdgcn_mfma_f32_16x16x32_bf16(ah1, bh, acc2[1][ni], 0, 0, 0);
            acc2[1][ni] = __builtin_amdgcn_mfma_f32_16x16x32_bf16(ah1, bl, acc2[1][ni], 0, 0, 0);
            acc2[1][ni] = __builtin_amdgcn_mfma_f32_16x16x32_bf16(al1, bh, acc2[1][ni], 0, 0, 0);
        }
    }

    // epilogue 2
    #pragma unroll
    for (int ni = 0; ni < 4; ++ni) {
        const int c = wn * 64 + ni * 16 + lr;
        const float s  = g2[c] * rsqrtf(v2[c] + BN_EPS);
        const float tt = be2[c] - m2[c] * s;
        const float bb = b2[c];
        #pragma unroll
        for (int mi = 0; mi < 2; ++mi)
            #pragma unroll
            for (int r = 0; r < 4; ++r)
                acc2[mi][ni][r] = fmaxf(fmaf(acc2[mi][ni][r] + bb, s, tt), 0.f);
    }

    // ---- Layer 3: A from acc2, accumulate into re-zeroed acc1 ----
    #pragma unroll
    for (int mi = 0; mi < 2; ++mi)
        #pragma unroll
        for (int ni = 0; ni < 4; ++ni)
            #pragma unroll
            for (int r = 0; r < 4; ++r)
                acc1[mi][ni][r] = 0.f;

    #pragma unroll
    for (int kc = 0; kc < 8; ++kc) {
        const f32x4* wsrc = reinterpret_cast<const f32x4*>(Wp + 196608 + kc * 16384);
        f32x4 wv0 = wsrc[tid], wv1 = wsrc[512 + tid];
        f32x4 wv2 = wsrc[1024 + tid], wv3 = wsrc[1536 + tid];
        __syncthreads();
        if (wn == (kc >> 1)) {
            #pragma unroll
            for (int j = 0; j < 2; ++j) {
                const int ni  = (kc & 1) * 2 + j;
                const int kgw = j * 2 + (lr >> 3);
                const int e   = lr & 7;
                #pragma unroll
                for (int mi = 0; mi < 2; ++mi)
                    #pragma unroll
                    for (int r = 0; r < 4; ++r) {
                        const float val = acc2[mi][ni][r];
                        const short h = f2bf(val);
                        Ab[0][wr][kgw][mi * 16 + kg * 4 + r][e] = (ushort)h;
                        Ab[1][wr][kgw][mi * 16 + kg * 4 + r][e] = (ushort)f2bf(val - bf2f(h));
                    }
            }
        }
        f32x4* wdst = reinterpret_cast<f32x4*>(Wb);
        wdst[tid] = wv0; wdst[512 + tid] = wv1;
        wdst[1024 + tid] = wv2; wdst[1536 + tid] = wv3;
        __syncthreads();

        bf16x8 ah0 = *reinterpret_cast<bf16x8*>(&Ab[0][wr][kg][lr][0]);
        bf16x8 al0 = *reinterpret_cast<bf16x8*>(&Ab[1][wr][kg][lr][0]);
        bf16x8 ah1 = *reinterpret_cast<bf16x8*>(&Ab[0][wr][kg][16 + lr][0]);
        bf16x8 al1 = *reinterpret_cast<bf16x8*>(&Ab[1][wr][kg][16 + lr][0]);
        #pragma unroll
        for (int ni = 0; ni < 4; ++ni) {
            bf16x8 bh = *reinterpret_cast<bf16x8*>(&Wb[0][kg][wn * 64 + ni * 16 + lr][0]);
            bf16x8 bl = *reinterpret_cast<bf16x8*>(&Wb[1][kg][wn * 64 + ni * 16 + lr][0]);
            acc1[0][ni] = __builtin_amdgcn_mfma_f32_16x16x32_bf16(ah0, bh, acc1[0][ni], 0, 0, 0);
            acc1[0][ni] = __builtin_amdgcn_mfma_f32_16x16x32_bf16(ah0, bl, acc1[0][ni], 0, 0, 0);
            acc1[0][ni] = __builtin_amdgcn_mfma_f32_16x16x32_bf16(al0, bh, acc1[0][ni], 0, 0, 0);
            acc1[1][ni] = __builtin_amdgcn_mfma_f32_16x16x32_bf16(ah1, bh, acc1[1][ni], 0, 0, 0);
            acc1[1][ni] = __builtin_amdgcn_mfma_f32_16x16x32_bf16(ah1, bl, acc1[1][ni], 0, 0, 0);
            acc1[1][ni] = __builtin_amdgcn_mfma_f32_16x16x32_bf16(al1, bh, acc1[1][ni], 0, 0, 0);
        }
    }

    // epilogue 3: bias+BN+relu -> wave max -> atomicMax pool
    const int b = blockIdx.x >> 4;
    #pragma unroll
    for (int ni = 0; ni < 4; ++ni) {
        const int c = wn * 64 + ni * 16 + lr;
        const float s  = g3[c] * rsqrtf(v3[c] + BN_EPS);
        const float tt = be3[c] - m3[c] * s;
        const float bb = b3[c];
        float mx = 0.0f;                 // relu floor
        #pragma unroll
        for (int mi = 0; mi < 2; ++mi)
            #pragma unroll
            for (int r = 0; r < 4; ++r)
                mx = fmaxf(mx, fmaf(acc1[mi][ni][r] + bb, s, tt));
        mx = fmaxf(mx, __shfl_xor(mx, 16));
        mx = fmaxf(mx, __shfl_xor(mx, 32));
        if (lane < 16)
            atomicMax((int*)&pool[b * 256 + c], __float_as_int(mx));
    }
}

// ---------------- K4: pool init (relu floor = 0) ----------------
__global__ __launch_bounds__(256) void pool_init(float* __restrict__ pool) {
    pool[blockIdx.x * 256 + threadIdx.x] = 0.0f;
}

// ---------------- K5: head Dense(3), wave-parallel ----------------
__global__ __launch_bounds__(256) void head_kernel(const float* __restrict__ pool,
                                                   const float* __restrict__ wd,
                                                   const float* __restrict__ bd,
                                                   float* __restrict__ out) {
    const int b = blockIdx.x;
    const int t = threadIdx.x;
    const int w = t >> 6;
    const int lane = t & 63;
    if (w < 3) {
        float s = 0.f;
        #pragma unroll
        for (int k = 0; k < 256; k += 64)
            s += pool[b * 256 + k + lane] * wd[(k + lane) * 3 + w];
        #pragma unroll
        for (int off = 32; off; off >>= 1) s += __shfl_down(s, off);
        if (lane == 0) out[b * 3 + w] = s + bd[w];
    }
}

extern "C" void kernel_launch(void* const* d_in, const int* in_sizes, int n_in,
                              void* d_out, int out_size, void* d_ws, size_t ws_size,
                              hipStream_t stream) {
    const float* x   = (const float*)d_in[0];
    const float* a   = (const float*)d_in[1];
    const float* eps = (const float*)d_in[2];
    const float* w1  = (const float*)d_in[3];
    const float* b1  = (const float*)d_in[4];
    const float* g1  = (const float*)d_in[5];
    const float* be1 = (const float*)d_in[6];
    const float* m1  = (const float*)d_in[7];
    const float* v1  = (const float*)d_in[8];
    const float* w2  = (const float*)d_in[9];
    const float* b2  = (const float*)d_in[10];
    const float* g2  = (const float*)d_in[11];
    const float* be2 = (const float*)d_in[12];
    const float* m2  = (const float*)d_in[13];
    const float* v2  = (const float*)d_in[14];
    const float* w3  = (const float*)d_in[15];
    const float* b3  = (const float*)d_in[16];
    const float* g3  = (const float*)d_in[17];
    const float* be3 = (const float*)d_in[18];
    const float* m3  = (const float*)d_in[19];
    const float* v3  = (const float*)d_in[20];
    const float* wd  = (const float*)d_in[21];
    const float* bd  = (const float*)d_in[22];
    float* out = (float*)d_out;

    // Workspace: h0 @0 (16MB), Wp @16M (640KB), Xp @18M (16MB), pool @34M (32KB)
    char* ws = (char*)d_ws;
    float*  h0   = (float*)(ws);
    ushort* Wp   = (ushort*)(ws + (16u << 20));
    ushort* Xp   = (ushort*)(ws + (18u << 20));
    float*  pool = (float*)(ws + (34u << 20));

    pool_init<<<32, 256, 0, stream>>>(pool);
    prep_w<<<640, 256, 0, stream>>>(w1, w2, w3, Wp);
    prep_x<<<1024, 512, 0, stream>>>(x, Xp);
    agg_mfma<<<512, 512, 0, stream>>>(x, a, Xp, eps, h0);
    fused_mlp<<<512, 512, 0, stream>>>(h0, Wp,
        b1, g1, be1, m1, v1,
        b2, g2, be2, m2, v2,
        b3, g3, be3, m3, v3, pool);
    head_kernel<<<32, 256, 0, stream>>>(pool, wd, bd, out);
}

// Round 7
// 304.937 us; speedup vs baseline: 1.0364x; 1.0364x over previous
//
#include <hip/hip_runtime.h>

#define BN_EPS 1e-3f

typedef __attribute__((ext_vector_type(8))) short bf16x8;
typedef __attribute__((ext_vector_type(4))) short short4v;
typedef __attribute__((ext_vector_type(4))) float f32x4;

__device__ __forceinline__ short f2bf(float f) {
    union { float f; unsigned u; } a; a.f = f;
    unsigned r = a.u + 0x7fffu + ((a.u >> 16) & 1u);
    return (short)(r >> 16);
}
__device__ __forceinline__ float bf2f(short s) {
    union { unsigned u; float f; } a;
    a.u = ((unsigned)(unsigned short)s) << 16;
    return a.f;
}

// ---------------- K0: pre-split x into hi/lo LDS chunk images ---------------
// Chunk image (8192 ushorts = 16KB): [plane][kg][f][e]; chunk c = b*32+kc.
__global__ __launch_bounds__(512) void prep_x(const float* __restrict__ x,
                                              ushort* __restrict__ Xp) {
    const int b  = blockIdx.x >> 5;
    const int kc = blockIdx.x & 31;
    const int t  = threadIdx.x;
    const int f  = t & 127;
    const int kg = t >> 7;             // 0..3
    bf16x8 hi8, lo8;
    #pragma unroll
    for (int e = 0; e < 8; ++e) {
        const float val = x[((size_t)b * 1024 + kc * 32 + kg * 8 + e) * 128 + f];
        const short h = f2bf(val);
        hi8[e] = h; lo8[e] = f2bf(val - bf2f(h));
    }
    const size_t base = ((size_t)(b * 32 + kc)) * 8192 + (size_t)kg * 1024 + (size_t)f * 8;
    *reinterpret_cast<bf16x8*>(&Xp[base])        = hi8;
    *reinterpret_cast<bf16x8*>(&Xp[base + 4096]) = lo8;
}

// ---------------- K1: GIN aggregation, 2-phase pipelined MFMA GEMM ----------
// BM=64, BK=64 (2 chunks/stage), 16 stages, ONE barrier per stage.
// 512 blocks = 32 b x 16 tiles; 8 waves = 4 rowgrp(16) x 2 colgrp(64).
__global__ __launch_bounds__(512, 4) void agg_mfma(
    const float* __restrict__ x, const float* __restrict__ a,
    const ushort* __restrict__ Xp, const float* __restrict__ epsp,
    float* __restrict__ h0) {
    __shared__ __align__(16) ushort Aab[2][2][4][64][8];        // 16 KB [buf][kc2][kg][row][e]
    __shared__ __align__(16) ushort Xhl[2][2][2][4][128][8];    // 64 KB [buf][kc2][plane][kg][f][e]

    const int tid  = threadIdx.x;
    const int lane = tid & 63;
    const int wid  = tid >> 6;
    const int wr   = wid >> 1;       // 0..3 (16 rows)
    const int wn   = wid & 1;        // 0..1 (64 f)
    const int lr   = lane & 15;
    const int kg   = lane >> 4;
    const int b    = blockIdx.x >> 4;
    const int row0 = (blockIdx.x & 15) * 64;

    const float*  ab = a + ((size_t)b * 1024 + row0) * 1024;
    const ushort* xp = Xp + (size_t)b * 32 * 8192;

    const int ar  = tid >> 3;        // 0..63 (a row)
    const int akq = tid & 7;         // k-quad (4 elems) within 32

    f32x4 acc[4] = {};

    // ---- staging helpers (macro to keep regs scalar-named) ----
#define AGG_LOAD(S, AV0, AV1, XV0, XV1, XV2, XV3)                                         \
    {   const float* ap_ = ab + (size_t)ar * 1024 + (S) * 64 + akq * 4;                   \
        AV0 = *reinterpret_cast<const f32x4*>(ap_);                                       \
        AV1 = *reinterpret_cast<const f32x4*>(ap_ + 32);                                  \
        const f32x4* x0_ = reinterpret_cast<const f32x4*>(xp + (size_t)((S)*2    ) * 8192);\
        const f32x4* x1_ = reinterpret_cast<const f32x4*>(xp + (size_t)((S)*2 + 1) * 8192);\
        XV0 = x0_[tid]; XV1 = x0_[512 + tid]; XV2 = x1_[tid]; XV3 = x1_[512 + tid]; }

#define AGG_WRITE(BUF, AV0, AV1, XV0, XV1, XV2, XV3)                                      \
    {   float f0_[4] = {AV0.x, AV0.y, AV0.z, AV0.w};                                      \
        float f1_[4] = {AV1.x, AV1.y, AV1.z, AV1.w};                                      \
        short4v h0_, h1_;                                                                 \
        _Pragma("unroll")                                                                 \
        for (int e = 0; e < 4; ++e) { h0_[e] = f2bf(f0_[e]); h1_[e] = f2bf(f1_[e]); }     \
        *reinterpret_cast<short4v*>(&Aab[BUF][0][akq >> 1][ar][(akq & 1) * 4]) = h0_;     \
        *reinterpret_cast<short4v*>(&Aab[BUF][1][akq >> 1][ar][(akq & 1) * 4]) = h1_;     \
        f32x4* xd_ = reinterpret_cast<f32x4*>(&Xhl[BUF][0][0][0][0][0]);                  \
        xd_[tid] = XV0; xd_[512 + tid] = XV1; xd_[1024 + tid] = XV2; xd_[1536 + tid] = XV3; }

    // prologue: stage 0 into buf 0
    f32x4 av0, av1, xv0, xv1, xv2, xv3;
    AGG_LOAD(0, av0, av1, xv0, xv1, xv2, xv3);
    AGG_WRITE(0, av0, av1, xv0, xv1, xv2, xv3);

    for (int s = 0; s < 16; ++s) {
        const int buf = s & 1;
        __syncthreads();                    // commits stage s; prev compute done
        f32x4 nav0, nav1, nxv0, nxv1, nxv2, nxv3;
        if (s + 1 < 16) AGG_LOAD(s + 1, nav0, nav1, nxv0, nxv1, nxv2, nxv3);

        bf16x8 af0 = *reinterpret_cast<bf16x8*>(&Aab[buf][0][kg][wr * 16 + lr][0]);
        bf16x8 af1 = *reinterpret_cast<bf16x8*>(&Aab[buf][1][kg][wr * 16 + lr][0]);
        #pragma unroll
        for (int ni = 0; ni < 4; ++ni) {
            const int c = wn * 64 + ni * 16 + lr;
            bf16x8 bh0 = *reinterpret_cast<bf16x8*>(&Xhl[buf][0][0][kg][c][0]);
            bf16x8 bl0 = *reinterpret_cast<bf16x8*>(&Xhl[buf][0][1][kg][c][0]);
            bf16x8 bh1 = *reinterpret_cast<bf16x8*>(&Xhl[buf][1][0][kg][c][0]);
            bf16x8 bl1 = *reinterpret_cast<bf16x8*>(&Xhl[buf][1][1][kg][c][0]);
            acc[ni] = __builtin_amdgcn_mfma_f32_16x16x32_bf16(af0, bh0, acc[ni], 0, 0, 0);
            acc[ni] = __builtin_amdgcn_mfma_f32_16x16x32_bf16(af0, bl0, acc[ni], 0, 0, 0);
            acc[ni] = __builtin_amdgcn_mfma_f32_16x16x32_bf16(af1, bh1, acc[ni], 0, 0, 0);
            acc[ni] = __builtin_amdgcn_mfma_f32_16x16x32_bf16(af1, bl1, acc[ni], 0, 0, 0);
        }

        if (s + 1 < 16) AGG_WRITE(buf ^ 1, nav0, nav1, nxv0, nxv1, nxv2, nxv3);
    }

    // epilogue: h0 = (1+eps)*x + agg  (verified C layout)
    const float ep1 = 1.0f + epsp[0];
    const float* xb = x + (size_t)b * 131072;
    #pragma unroll
    for (int ni = 0; ni < 4; ++ni) {
        const int col   = wn * 64 + ni * 16 + lr;
        const int rbase = row0 + wr * 16 + kg * 4;
        #pragma unroll
        for (int r = 0; r < 4; ++r) {
            const size_t off = (size_t)(rbase + r) * 128 + col;
            h0[(size_t)b * 131072 + off] = fmaf(ep1, xb[off], acc[ni][r]);
        }
    }
#undef AGG_LOAD
#undef AGG_WRITE
}

// ---------------- K2: W pre-split into LDS chunk images (verified) --------
__global__ __launch_bounds__(256) void prep_w(
    const float* __restrict__ w1, const float* __restrict__ w2,
    const float* __restrict__ w3, ushort* __restrict__ Wp) {
    const int k = blockIdx.x;      // 0..639 global k row
    const int c = threadIdx.x;     // 0..255
    const float* src; int kl, base;
    if (k < 128)      { src = w1; kl = k;       base = 0; }
    else if (k < 384) { src = w2; kl = k - 128; base = 65536; }
    else              { src = w3; kl = k - 384; base = 196608; }
    const float val = src[(size_t)kl * 256 + c];
    const short hi = f2bf(val);
    const short lo = f2bf(val - bf2f(hi));
    const int off = base + (kl >> 5) * 16384 + ((((kl >> 3) & 3) * 256 + c) * 8) + (kl & 7);
    Wp[off]        = (ushort)hi;
    Wp[off + 8192] = (ushort)lo;
}

// ---------------- K3: fused 3-layer MLP + max-pool, 2-phase pipelined ------
// 512 blocks x 512 thr; 8 waves = 2 rowgrp(32) x 4 colgrp(64).
// 20 chunk-stages total (L1:4, L2:8, L3:8), ONE barrier per stage;
// Wb/Ab double-buffered; W prefetched 1 chunk ahead in regs.
__global__ __launch_bounds__(512, 4) void fused_mlp(
    const float* __restrict__ h0, const ushort* __restrict__ Wp,
    const float* __restrict__ b1, const float* __restrict__ g1,
    const float* __restrict__ be1, const float* __restrict__ m1,
    const float* __restrict__ v1,
    const float* __restrict__ b2, const float* __restrict__ g2,
    const float* __restrict__ be2, const float* __restrict__ m2,
    const float* __restrict__ v2,
    const float* __restrict__ b3, const float* __restrict__ g3,
    const float* __restrict__ be3, const float* __restrict__ m3,
    const float* __restrict__ v3,
    float* __restrict__ pool) {
    __shared__ __align__(16) ushort Wb[2][2][4][256][8];   // 64KB [buf][plane][kg][c][e]
    __shared__ __align__(16) ushort Ab[2][2][2][4][32][8]; // 16KB [buf][plane][wr][kg][row][e]

    const int tid  = threadIdx.x;
    const int lane = tid & 63;
    const int wid  = tid >> 6;
    const int wr   = wid >> 2;     // 0..1 (32 rows)
    const int wn   = wid & 3;      // 0..3 (64 cols)
    const int lr   = lane & 15;
    const int kg   = lane >> 4;
    const int row0 = blockIdx.x * 64;

    const int ar  = tid >> 3;      // 0..63
    const int akq = tid & 7;

    f32x4 acc1[2][4] = {};
    f32x4 acc2[2][4] = {};

#define MLP_LOADW(BASE, KC, W0, W1, W2, W3)                                               \
    {   const f32x4* ws_ = reinterpret_cast<const f32x4*>(Wp + (BASE) + (KC) * 16384);    \
        W0 = ws_[tid]; W1 = ws_[512 + tid]; W2 = ws_[1024 + tid]; W3 = ws_[1536 + tid]; }

#define MLP_WRITEW(BUF, W0, W1, W2, W3)                                                   \
    {   f32x4* wd_ = reinterpret_cast<f32x4*>(&Wb[BUF][0][0][0][0]);                      \
        wd_[tid] = W0; wd_[512 + tid] = W1; wd_[1024 + tid] = W2; wd_[1536 + tid] = W3; }

#define MLP_LOADA1(KC, AV)                                                                \
    AV = *reinterpret_cast<const f32x4*>(h0 + (size_t)(row0 + ar) * 128 + (KC) * 32 + akq * 4);

#define MLP_WRITEA1(BUF, AV)                                                              \
    {   float fx_[4] = {AV.x, AV.y, AV.z, AV.w};                                          \
        short4v h4_, l4_;                                                                 \
        _Pragma("unroll")                                                                 \
        for (int e = 0; e < 4; ++e) {                                                     \
            const short h_ = f2bf(fx_[e]);                                                \
            h4_[e] = h_; l4_[e] = f2bf(fx_[e] - bf2f(h_));                                \
        }                                                                                 \
        *reinterpret_cast<short4v*>(&Ab[BUF][0][ar >> 5][akq >> 1][ar & 31][(akq & 1) * 4]) = h4_; \
        *reinterpret_cast<short4v*>(&Ab[BUF][1][ar >> 5][akq >> 1][ar & 31][(akq & 1) * 4]) = l4_; }

    // redistribute chunk KC of next layer's A from accumulator SRC into Ab[BUF]
#define MLP_REDIST(BUF, KC, SRC)                                                          \
    if (wn == ((KC) >> 1)) {                                                              \
        _Pragma("unroll")                                                                 \
        for (int j = 0; j < 2; ++j) {                                                     \
            const int ni  = ((KC) & 1) * 2 + j;                                           \
            const int kgw = j * 2 + (lr >> 3);                                            \
            const int e   = lr & 7;                                                       \
            _Pragma("unroll")                                                             \
            for (int mi = 0; mi < 2; ++mi)                                                \
                _Pragma("unroll")                                                         \
                for (int r = 0; r < 4; ++r) {                                             \
                    const float val_ = SRC[mi][ni][r];                                    \
                    const short h_ = f2bf(val_);                                          \
                    Ab[BUF][0][wr][kgw][mi * 16 + kg * 4 + r][e] = (ushort)h_;            \
                    Ab[BUF][1][wr][kgw][mi * 16 + kg * 4 + r][e] = (ushort)f2bf(val_ - bf2f(h_)); \
                }                                                                         \
        }                                                                                 \
    }

#define MLP_COMPUTE(BUF, DST)                                                             \
    {   bf16x8 ah0 = *reinterpret_cast<bf16x8*>(&Ab[BUF][0][wr][kg][lr][0]);              \
        bf16x8 al0 = *reinterpret_cast<bf16x8*>(&Ab[BUF][1][wr][kg][lr][0]);              \
        bf16x8 ah1 = *reinterpret_cast<bf16x8*>(&Ab[BUF][0][wr][kg][16 + lr][0]);         \
        bf16x8 al1 = *reinterpret_cast<bf16x8*>(&Ab[BUF][1][wr][kg][16 + lr][0]);         \
        _Pragma("unroll")                                                                 \
        for (int ni = 0; ni < 4; ++ni) {                                                  \
            bf16x8 bh = *reinterpret_cast<bf16x8*>(&Wb[BUF][0][kg][wn * 64 + ni * 16 + lr][0]); \
            bf16x8 bl = *reinterpret_cast<bf16x8*>(&Wb[BUF][1][kg][wn * 64 + ni * 16 + lr][0]); \
            DST[0][ni] = __builtin_amdgcn_mfma_f32_16x16x32_bf16(ah0, bh, DST[0][ni], 0, 0, 0); \
            DST[0][ni] = __builtin_amdgcn_mfma_f32_16x16x32_bf16(ah0, bl, DST[0][ni], 0, 0, 0); \
            DST[0][ni] = __builtin_amdgcn_mfma_f32_16x16x32_bf16(al0, bh, DST[0][ni], 0, 0, 0); \
            DST[1][ni] = __builtin_amdgcn_mfma_f32_16x16x32_bf16(ah1, bh, DST[1][ni], 0, 0, 0); \
            DST[1][ni] = __builtin_amdgcn_mfma_f32_16x16x32_bf16(ah1, bl, DST[1][ni], 0, 0, 0); \
            DST[1][ni] = __builtin_amdgcn_mfma_f32_16x16x32_bf16(al1, bh, DST[1][ni], 0, 0, 0); \
        }                                                                                 \
    }

#define MLP_BN(ACC, G, V, BE, M, BI)                                                      \
    _Pragma("unroll")                                                                     \
    for (int ni = 0; ni < 4; ++ni) {                                                      \
        const int c = wn * 64 + ni * 16 + lr;                                             \
        const float s_  = G[c] * rsqrtf(V[c] + BN_EPS);                                   \
        const float tt_ = BE[c] - M[c] * s_;                                              \
        const float bb_ = BI[c];                                                          \
        _Pragma("unroll")                                                                 \
        for (int mi = 0; mi < 2; ++mi)                                                    \
            _Pragma("unroll")                                                             \
            for (int r = 0; r < 4; ++r)                                                   \
                ACC[mi][ni][r] = fmaxf(fmaf(ACC[mi][ni][r] + bb_, s_, tt_), 0.f);         \
    }

    f32x4 wv0, wv1, wv2, wv3, wn0, wn1, wn2, wn3, av, avn;

    // ---- prologue: stage L1 chunk 0 into buf 0 ----
    MLP_LOADW(0, 0, wv0, wv1, wv2, wv3);
    MLP_LOADA1(0, av);
    MLP_WRITEW(0, wv0, wv1, wv2, wv3);
    MLP_WRITEA1(0, av);

    // ---- Layer 1: 4 chunk-stages ----
    #pragma unroll
    for (int s = 0; s < 4; ++s) {
        const int buf = s & 1;
        __syncthreads();
        if (s < 3) { MLP_LOADW(0, s + 1, wn0, wn1, wn2, wn3); MLP_LOADA1(s + 1, avn); }
        else       { MLP_LOADW(65536, 0, wn0, wn1, wn2, wn3); }
        MLP_COMPUTE(buf, acc1);
        MLP_WRITEW(buf ^ 1, wn0, wn1, wn2, wn3);
        if (s < 3) MLP_WRITEA1(buf ^ 1, avn);
    }
    MLP_BN(acc1, g1, v1, be1, m1, b1);
    MLP_REDIST(0, 0, acc1);          // A(L2, chunk0) -> Ab[0]

    // ---- Layer 2: 8 chunk-stages ----
    #pragma unroll
    for (int s = 0; s < 8; ++s) {
        const int buf = s & 1;
        __syncthreads();
        if (s < 7) { MLP_LOADW(65536, s + 1, wn0, wn1, wn2, wn3); }
        else       { MLP_LOADW(196608, 0, wn0, wn1, wn2, wn3); }
        MLP_COMPUTE(buf, acc2);
        MLP_WRITEW(buf ^ 1, wn0, wn1, wn2, wn3);
        if (s < 7) MLP_REDIST(buf ^ 1, s + 1, acc1);
    }
    MLP_BN(acc2, g2, v2, be2, m2, b2);

    // ---- Layer 3: reuse acc1 as accumulator ----
    #pragma unroll
    for (int mi = 0; mi < 2; ++mi)
        #pragma unroll
        for (int ni = 0; ni < 4; ++ni)
            #pragma unroll
            for (int r = 0; r < 4; ++r)
                acc1[mi][ni][r] = 0.f;
    MLP_REDIST(0, 0, acc2);          // A(L3, chunk0) -> Ab[0]

    #pragma unroll
    for (int s = 0; s < 8; ++s) {
        const int buf = s & 1;
        __syncthreads();
        if (s < 7) { MLP_LOADW(196608, s + 1, wn0, wn1, wn2, wn3); }
        MLP_COMPUTE(buf, acc1);
        if (s < 7) {
            MLP_WRITEW(buf ^ 1, wn0, wn1, wn2, wn3);
            MLP_REDIST(buf ^ 1, s + 1, acc2);
        }
    }

    // epilogue 3: bias+BN+relu -> wave max -> atomicMax pool
    const int b = blockIdx.x >> 4;
    #pragma unroll
    for (int ni = 0; ni < 4; ++ni) {
        const int c = wn * 64 + ni * 16 + lr;
        const float s  = g3[c] * rsqrtf(v3[c] + BN_EPS);
        const float tt = be3[c] - m3[c] * s;
        const float bb = b3[c];
        float mx = 0.0f;                 // relu floor
        #pragma unroll
        for (int mi = 0; mi < 2; ++mi)
            #pragma unroll
            for (int r = 0; r < 4; ++r)
                mx = fmaxf(mx, fmaf(acc1[mi][ni][r] + bb, s, tt));
        mx = fmaxf(mx, __shfl_xor(mx, 16));
        mx = fmaxf(mx, __shfl_xor(mx, 32));
        if (lane < 16)
            atomicMax((int*)&pool[b * 256 + c], __float_as_int(mx));
    }
}

// ---------------- K4: pool init (relu floor = 0) ----------------
__global__ __launch_bounds__(256) void pool_init(float* __restrict__ pool) {
    pool[blockIdx.x * 256 + threadIdx.x] = 0.0f;
}

// ---------------- K5: head Dense(3), wave-parallel ----------------
__global__ __launch_bounds__(256) void head_kernel(const float* __restrict__ pool,
                                                   const float* __restrict__ wd,
                                                   const float* __restrict__ bd,
                                                   float* __restrict__ out) {
    const int b = blockIdx.x;
    const int t = threadIdx.x;
    const int w = t >> 6;
    const int lane = t & 63;
    if (w < 3) {
        float s = 0.f;
        #pragma unroll
        for (int k = 0; k < 256; k += 64)
            s += pool[b * 256 + k + lane] * wd[(k + lane) * 3 + w];
        #pragma unroll
        for (int off = 32; off; off >>= 1) s += __shfl_down(s, off);
        if (lane == 0) out[b * 3 + w] = s + bd[w];
    }
}

extern "C" void kernel_launch(void* const* d_in, const int* in_sizes, int n_in,
                              void* d_out, int out_size, void* d_ws, size_t ws_size,
                              hipStream_t stream) {
    const float* x   = (const float*)d_in[0];
    const float* a   = (const float*)d_in[1];
    const float* eps = (const float*)d_in[2];
    const float* w1  = (const float*)d_in[3];
    const float* b1  = (const float*)d_in[4];
    const float* g1  = (const float*)d_in[5];
    const float* be1 = (const float*)d_in[6];
    const float* m1  = (const float*)d_in[7];
    const float* v1  = (const float*)d_in[8];
    const float* w2  = (const float*)d_in[9];
    const float* b2  = (const float*)d_in[10];
    const float* g2  = (const float*)d_in[11];
    const float* be2 = (const float*)d_in[12];
    const float* m2  = (const float*)d_in[13];
    const float* v2  = (const float*)d_in[14];
    const float* w3  = (const float*)d_in[15];
    const float* b3  = (const float*)d_in[16];
    const float* g3  = (const float*)d_in[17];
    const float* be3 = (const float*)d_in[18];
    const float* m3  = (const float*)d_in[19];
    const float* v3  = (const float*)d_in[20];
    const float* wd  = (const float*)d_in[21];
    const float* bd  = (const float*)d_in[22];
    float* out = (float*)d_out;

    // Workspace: h0 @0 (16MB), Wp @16M (640KB), Xp @18M (16MB), pool @34M (32KB)
    char* ws = (char*)d_ws;
    float*  h0   = (float*)(ws);
    ushort* Wp   = (ushort*)(ws + (16u << 20));
    ushort* Xp   = (ushort*)(ws + (18u << 20));
    float*  pool = (float*)(ws + (34u << 20));

    pool_init<<<32, 256, 0, stream>>>(pool);
    prep_w<<<640, 256, 0, stream>>>(w1, w2, w3, Wp);
    prep_x<<<1024, 512, 0, stream>>>(x, Xp);
    agg_mfma<<<512, 512, 0, stream>>>(x, a, Xp, eps, h0);
    fused_mlp<<<512, 512, 0, stream>>>(h0, Wp,
        b1, g1, be1, m1, v1,
        b2, g2, be2, m2, v2,
        b3, g3, be3, m3, v3, pool);
    head_kernel<<<32, 256, 0, stream>>>(pool, wd, bd, out);
}

// Round 8
// 296.087 us; speedup vs baseline: 1.0674x; 1.0299x over previous
//
#include <hip/hip_runtime.h>

#define BN_EPS 1e-3f

typedef __attribute__((ext_vector_type(8))) short bf16x8;
typedef __attribute__((ext_vector_type(4))) short short4v;
typedef __attribute__((ext_vector_type(4))) float f32x4;

__device__ __forceinline__ short f2bf(float f) {
    union { float f; unsigned u; } a; a.f = f;
    unsigned r = a.u + 0x7fffu + ((a.u >> 16) & 1u);
    return (short)(r >> 16);
}
__device__ __forceinline__ float bf2f(short s) {
    union { unsigned u; float f; } a;
    a.u = ((unsigned)(unsigned short)s) << 16;
    return a.f;
}
__device__ __forceinline__ f32x4 ntload4(const float* p) {
    return __builtin_nontemporal_load(reinterpret_cast<const f32x4*>(p));
}

// ---------------- K0: pre-split x into hi/lo LDS chunk images ---------------
// Chunk image (8192 ushorts = 16KB): [plane][kg][f][e]; chunk c = b*32+kc.
__global__ __launch_bounds__(512) void prep_x(const float* __restrict__ x,
                                              ushort* __restrict__ Xp) {
    const int b  = blockIdx.x >> 5;
    const int kc = blockIdx.x & 31;
    const int t  = threadIdx.x;
    const int f  = t & 127;
    const int kg = t >> 7;             // 0..3
    bf16x8 hi8, lo8;
    #pragma unroll
    for (int e = 0; e < 8; ++e) {
        const float val = x[((size_t)b * 1024 + kc * 32 + kg * 8 + e) * 128 + f];
        const short h = f2bf(val);
        hi8[e] = h; lo8[e] = f2bf(val - bf2f(h));
    }
    const size_t base = ((size_t)(b * 32 + kc)) * 8192 + (size_t)kg * 1024 + (size_t)f * 8;
    *reinterpret_cast<bf16x8*>(&Xp[base])        = hi8;
    *reinterpret_cast<bf16x8*>(&Xp[base + 4096]) = lo8;
}

// ---------------- K2: W pre-split into LDS chunk images (verified) --------
__global__ __launch_bounds__(256) void prep_w(
    const float* __restrict__ w1, const float* __restrict__ w2,
    const float* __restrict__ w3, ushort* __restrict__ Wp) {
    const int k = blockIdx.x;      // 0..639 global k row
    const int c = threadIdx.x;     // 0..255
    const float* src; int kl, base;
    if (k < 128)      { src = w1; kl = k;       base = 0; }
    else if (k < 384) { src = w2; kl = k - 128; base = 65536; }
    else              { src = w3; kl = k - 384; base = 196608; }
    const float val = src[(size_t)kl * 256 + c];
    const short hi = f2bf(val);
    const short lo = f2bf(val - bf2f(hi));
    const int off = base + (kl >> 5) * 16384 + ((((kl >> 3) & 3) * 256 + c) * 8) + (kl & 7);
    Wp[off]        = (ushort)hi;
    Wp[off + 8192] = (ushort)lo;
}

// ---------------- MEGA: agg + 3-layer MLP + max-pool, one kernel -----------
// 512 blocks x 512 thr (8 waves). XCD-aware: batch pinned to one XCD.
// Phase A: agg over K=1024 split in 2 k-halves; waves = 2wr x (2fg x 2kh).
// Cross-wave k-half reduction in LDS, x-epilogue in regs, REDIST -> L1.
// Phase B: r7's verified pipelined 3-layer MLP (L1 A via REDIST from regs).
__global__ __launch_bounds__(512, 4) void mega_gin(
    const float* __restrict__ x, const float* __restrict__ a,
    const ushort* __restrict__ Xp, const ushort* __restrict__ Wp,
    const float* __restrict__ epsp,
    const float* __restrict__ b1, const float* __restrict__ g1,
    const float* __restrict__ be1, const float* __restrict__ m1,
    const float* __restrict__ v1,
    const float* __restrict__ b2, const float* __restrict__ g2,
    const float* __restrict__ be2, const float* __restrict__ m2,
    const float* __restrict__ v2,
    const float* __restrict__ b3, const float* __restrict__ g3,
    const float* __restrict__ be3, const float* __restrict__ m3,
    const float* __restrict__ v3,
    float* __restrict__ pool) {

    // 80 KB LDS union (aliasing is barrier-separated; see transition notes)
    __shared__ __align__(16) char smem[81920];
    auto Aab = reinterpret_cast<ushort(*)[2][4][64][8]>(smem);            // [buf][half][kg][row][e]   16 KB
    auto Xhl = reinterpret_cast<ushort(*)[2][2][4][128][8]>(smem + 16384);// [buf][half][pl][kg][f][e] 64 KB
    auto Red = reinterpret_cast<f32x4(*)[2][64][8]>(smem);                // [wr][fg][lane][frag]      16 KB
    auto Wb  = reinterpret_cast<ushort(*)[2][4][256][8]>(smem);           // [buf][pl][kg][c][e]       64 KB
    auto Ab  = reinterpret_cast<ushort(*)[2][2][4][32][8]>(smem + 65536); // [buf][pl][wr][kg][row][e] 16 KB

    const int tid  = threadIdx.x;
    const int lane = tid & 63;
    const int wid  = tid >> 6;
    const int wr   = wid >> 2;       // 0..1: 32-row group (both phases)
    const int wn   = wid & 3;        // phase B col-group (64 cols)
    const int fg   = wid & 1;        // phase A f-group (64 f)
    const int kh   = (wid >> 1) & 1; // phase A k-half (512 nodes)
    const int lr   = lane & 15;
    const int kg   = lane >> 4;

    // XCD-aware block mapping: all 16 tiles of a batch on one XCD
    const int xcd   = blockIdx.x & 7;
    const int idx   = blockIdx.x >> 3;
    const int batch = xcd * 4 + (idx & 3);
    const int tile  = idx >> 2;          // 0..15
    const int row0  = tile * 64;

    const float*  ab = a + ((size_t)batch * 1024 + row0) * 1024;
    const ushort* xp = Xp + (size_t)batch * 32 * 8192;

    const int ar  = tid >> 3;        // 0..63 (a row)
    const int akq = tid & 7;         // k-quad (4 elems) within 32

    f32x4 aa[2][4] = {};             // agg accumulator

#define AGG_LOAD(S, A0, A1, X0, X1, X2, X3)                                               \
    {   const float* ap_ = ab + (size_t)ar * 1024 + (S) * 32 + akq * 4;                   \
        A0 = ntload4(ap_);           /* half0: k = S*32+akq*4      */                     \
        A1 = ntload4(ap_ + 512);     /* half1: k = 512+S*32+akq*4  */                     \
        const f32x4* x0_ = reinterpret_cast<const f32x4*>(xp + (size_t)(S) * 8192);       \
        const f32x4* x1_ = reinterpret_cast<const f32x4*>(xp + (size_t)(16 + (S)) * 8192);\
        X0 = x0_[tid]; X1 = x0_[512 + tid]; X2 = x1_[tid]; X3 = x1_[512 + tid]; }

#define AGG_WRITE(BUF, A0, A1, X0, X1, X2, X3)                                            \
    {   float f0_[4] = {A0.x, A0.y, A0.z, A0.w};                                          \
        float f1_[4] = {A1.x, A1.y, A1.z, A1.w};                                          \
        short4v h0_, h1_;                                                                 \
        _Pragma("unroll")                                                                 \
        for (int e = 0; e < 4; ++e) { h0_[e] = f2bf(f0_[e]); h1_[e] = f2bf(f1_[e]); }     \
        *reinterpret_cast<short4v*>(&Aab[BUF][0][akq >> 1][ar][(akq & 1) * 4]) = h0_;     \
        *reinterpret_cast<short4v*>(&Aab[BUF][1][akq >> 1][ar][(akq & 1) * 4]) = h1_;     \
        f32x4* xd_ = reinterpret_cast<f32x4*>(&Xhl[BUF][0][0][0][0][0]);                  \
        xd_[tid] = X0; xd_[512 + tid] = X1; xd_[1024 + tid] = X2; xd_[1536 + tid] = X3; }

    // ---- Phase A: 16 stages, dbuf, one barrier per stage ----
    f32x4 av0, av1, xv0, xv1, xv2, xv3;
    AGG_LOAD(0, av0, av1, xv0, xv1, xv2, xv3);
    AGG_WRITE(0, av0, av1, xv0, xv1, xv2, xv3);

    for (int s = 0; s < 16; ++s) {
        const int buf = s & 1;
        __syncthreads();
        f32x4 na0, na1, nx0, nx1, nx2, nx3;
        if (s + 1 < 16) AGG_LOAD(s + 1, na0, na1, nx0, nx1, nx2, nx3);

        bf16x8 af0 = *reinterpret_cast<bf16x8*>(&Aab[buf][kh][kg][wr * 32 + lr][0]);
        bf16x8 af1 = *reinterpret_cast<bf16x8*>(&Aab[buf][kh][kg][wr * 32 + 16 + lr][0]);
        #pragma unroll
        for (int ni = 0; ni < 4; ++ni) {
            const int c = fg * 64 + ni * 16 + lr;
            bf16x8 bh = *reinterpret_cast<bf16x8*>(&Xhl[buf][kh][0][kg][c][0]);
            bf16x8 bl = *reinterpret_cast<bf16x8*>(&Xhl[buf][kh][1][kg][c][0]);
            aa[0][ni] = __builtin_amdgcn_mfma_f32_16x16x32_bf16(af0, bh, aa[0][ni], 0, 0, 0);
            aa[0][ni] = __builtin_amdgcn_mfma_f32_16x16x32_bf16(af0, bl, aa[0][ni], 0, 0, 0);
            aa[1][ni] = __builtin_amdgcn_mfma_f32_16x16x32_bf16(af1, bh, aa[1][ni], 0, 0, 0);
            aa[1][ni] = __builtin_amdgcn_mfma_f32_16x16x32_bf16(af1, bl, aa[1][ni], 0, 0, 0);
        }
        if (s + 1 < 16) AGG_WRITE(buf ^ 1, na0, na1, nx0, nx1, nx2, nx3);
    }

    // ---- Phase B macros (r7 verified) ----
    f32x4 acc1[2][4] = {};
    f32x4 acc2[2][4] = {};

#define MLP_LOADW(BASE, KC, W0, W1, W2, W3)                                               \
    {   const f32x4* ws_ = reinterpret_cast<const f32x4*>(Wp + (BASE) + (KC) * 16384);    \
        W0 = ws_[tid]; W1 = ws_[512 + tid]; W2 = ws_[1024 + tid]; W3 = ws_[1536 + tid]; }

#define MLP_WRITEW(BUF, W0, W1, W2, W3)                                                   \
    {   f32x4* wd_ = reinterpret_cast<f32x4*>(&Wb[BUF][0][0][0][0]);                      \
        wd_[tid] = W0; wd_[512 + tid] = W1; wd_[1024 + tid] = W2; wd_[1536 + tid] = W3; }

#define MLP_REDIST(BUF, KC, SRC)                                                          \
    if (wn == ((KC) >> 1)) {                                                              \
        _Pragma("unroll")                                                                 \
        for (int j = 0; j < 2; ++j) {                                                     \
            const int ni  = ((KC) & 1) * 2 + j;                                           \
            const int kgw = j * 2 + (lr >> 3);                                            \
            const int e   = lr & 7;                                                       \
            _Pragma("unroll")                                                             \
            for (int mi = 0; mi < 2; ++mi)                                                \
                _Pragma("unroll")                                                         \
                for (int r = 0; r < 4; ++r) {                                             \
                    const float val_ = SRC[mi][ni][r];                                    \
                    const short h_ = f2bf(val_);                                          \
                    Ab[BUF][0][wr][kgw][mi * 16 + kg * 4 + r][e] = (ushort)h_;            \
                    Ab[BUF][1][wr][kgw][mi * 16 + kg * 4 + r][e] = (ushort)f2bf(val_ - bf2f(h_)); \
                }                                                                         \
        }                                                                                 \
    }

#define MLP_COMPUTE(BUF, DST)                                                             \
    {   bf16x8 ah0 = *reinterpret_cast<bf16x8*>(&Ab[BUF][0][wr][kg][lr][0]);              \
        bf16x8 al0 = *reinterpret_cast<bf16x8*>(&Ab[BUF][1][wr][kg][lr][0]);              \
        bf16x8 ah1 = *reinterpret_cast<bf16x8*>(&Ab[BUF][0][wr][kg][16 + lr][0]);         \
        bf16x8 al1 = *reinterpret_cast<bf16x8*>(&Ab[BUF][1][wr][kg][16 + lr][0]);         \
        _Pragma("unroll")                                                                 \
        for (int ni = 0; ni < 4; ++ni) {                                                  \
            bf16x8 bh = *reinterpret_cast<bf16x8*>(&Wb[BUF][0][kg][wn * 64 + ni * 16 + lr][0]); \
            bf16x8 bl = *reinterpret_cast<bf16x8*>(&Wb[BUF][1][kg][wn * 64 + ni * 16 + lr][0]); \
            DST[0][ni] = __builtin_amdgcn_mfma_f32_16x16x32_bf16(ah0, bh, DST[0][ni], 0, 0, 0); \
            DST[0][ni] = __builtin_amdgcn_mfma_f32_16x16x32_bf16(ah0, bl, DST[0][ni], 0, 0, 0); \
            DST[0][ni] = __builtin_amdgcn_mfma_f32_16x16x32_bf16(al0, bh, DST[0][ni], 0, 0, 0); \
            DST[1][ni] = __builtin_amdgcn_mfma_f32_16x16x32_bf16(ah1, bh, DST[1][ni], 0, 0, 0); \
            DST[1][ni] = __builtin_amdgcn_mfma_f32_16x16x32_bf16(ah1, bl, DST[1][ni], 0, 0, 0); \
            DST[1][ni] = __builtin_amdgcn_mfma_f32_16x16x32_bf16(al1, bh, DST[1][ni], 0, 0, 0); \
        }                                                                                 \
    }

#define MLP_BN(ACC, G, V, BE, M, BI)                                                      \
    _Pragma("unroll")                                                                     \
    for (int ni = 0; ni < 4; ++ni) {                                                      \
        const int c = wn * 64 + ni * 16 + lr;                                             \
        const float s_  = G[c] * rsqrtf(V[c] + BN_EPS);                                   \
        const float tt_ = BE[c] - M[c] * s_;                                              \
        const float bb_ = BI[c];                                                          \
        _Pragma("unroll")                                                                 \
        for (int mi = 0; mi < 2; ++mi)                                                    \
            _Pragma("unroll")                                                             \
            for (int r = 0; r < 4; ++r)                                                   \
                ACC[mi][ni][r] = fmaxf(fmaf(ACC[mi][ni][r] + bb_, s_, tt_), 0.f);         \
    }

    f32x4 wv0, wv1, wv2, wv3, wn0, wn1, wn2, wn3;

    // ---- Transition: reduce k-halves, x-epilogue, REDIST -> L1 chunk 0 ----
    MLP_LOADW(0, 0, wv0, wv1, wv2, wv3);     // issue early (reg-only, hides L2 latency)
    __syncthreads();                         // phase A reads of Aab/Xhl complete
    if (kh == 1) {
        #pragma unroll
        for (int mi = 0; mi < 2; ++mi)
            #pragma unroll
            for (int ni = 0; ni < 4; ++ni)
                Red[wr][fg][lane][mi * 4 + ni] = aa[mi][ni];
    }
    __syncthreads();
    if (kh == 0) {
        const float ep1 = 1.0f + epsp[0];
        const float* xb = x + (size_t)batch * 131072;
        #pragma unroll
        for (int ni = 0; ni < 4; ++ni) {
            const int col = fg * 64 + ni * 16 + lr;
            #pragma unroll
            for (int mi = 0; mi < 2; ++mi) {
                const int rbase = row0 + wr * 32 + mi * 16 + kg * 4;
                #pragma unroll
                for (int r = 0; r < 4; ++r) {
                    float t = aa[mi][ni][r] + Red[wr][fg][lane][mi * 4 + ni][r];
                    aa[mi][ni][r] = fmaf(ep1, xb[(size_t)(rbase + r) * 128 + col], t);
                }
            }
        }
        MLP_REDIST(0, 0, aa);               // Ab region = dead Xhl top; ok pre-barrier
    }
    __syncthreads();                         // Red consumed; Ab[0] visible next barrier
    MLP_WRITEW(0, wv0, wv1, wv2, wv3);       // Wb[0] clobbers Red (safe post-barrier)

    // ---- Layer 1: 4 chunk-stages (A via REDIST from aa) ----
    #pragma unroll
    for (int s = 0; s < 4; ++s) {
        const int buf = s & 1;
        __syncthreads();
        if (s < 3) { MLP_LOADW(0, s + 1, wn0, wn1, wn2, wn3); }
        else       { MLP_LOADW(65536, 0, wn0, wn1, wn2, wn3); }
        MLP_COMPUTE(buf, acc1);
        MLP_WRITEW(buf ^ 1, wn0, wn1, wn2, wn3);
        if (s < 3) MLP_REDIST(buf ^ 1, s + 1, aa);
    }
    MLP_BN(acc1, g1, v1, be1, m1, b1);
    MLP_REDIST(0, 0, acc1);

    // ---- Layer 2: 8 chunk-stages ----
    #pragma unroll
    for (int s = 0; s < 8; ++s) {
        const int buf = s & 1;
        __syncthreads();
        if (s < 7) { MLP_LOADW(65536, s + 1, wn0, wn1, wn2, wn3); }
        else       { MLP_LOADW(196608, 0, wn0, wn1, wn2, wn3); }
        MLP_COMPUTE(buf, acc2);
        MLP_WRITEW(buf ^ 1, wn0, wn1, wn2, wn3);
        if (s < 7) MLP_REDIST(buf ^ 1, s + 1, acc1);
    }
    MLP_BN(acc2, g2, v2, be2, m2, b2);

    // ---- Layer 3 ----
    #pragma unroll
    for (int mi = 0; mi < 2; ++mi)
        #pragma unroll
        for (int ni = 0; ni < 4; ++ni)
            #pragma unroll
            for (int r = 0; r < 4; ++r)
                acc1[mi][ni][r] = 0.f;
    MLP_REDIST(0, 0, acc2);

    #pragma unroll
    for (int s = 0; s < 8; ++s) {
        const int buf = s & 1;
        __syncthreads();
        if (s < 7) { MLP_LOADW(196608, s + 1, wn0, wn1, wn2, wn3); }
        MLP_COMPUTE(buf, acc1);
        if (s < 7) {
            MLP_WRITEW(buf ^ 1, wn0, wn1, wn2, wn3);
            MLP_REDIST(buf ^ 1, s + 1, acc2);
        }
    }

    // epilogue 3: bias+BN+relu -> wave max -> atomicMax pool
    #pragma unroll
    for (int ni = 0; ni < 4; ++ni) {
        const int c = wn * 64 + ni * 16 + lr;
        const float s  = g3[c] * rsqrtf(v3[c] + BN_EPS);
        const float tt = be3[c] - m3[c] * s;
        const float bb = b3[c];
        float mx = 0.0f;                 // relu floor
        #pragma unroll
        for (int mi = 0; mi < 2; ++mi)
            #pragma unroll
            for (int r = 0; r < 4; ++r)
                mx = fmaxf(mx, fmaf(acc1[mi][ni][r] + bb, s, tt));
        mx = fmaxf(mx, __shfl_xor(mx, 16));
        mx = fmaxf(mx, __shfl_xor(mx, 32));
        if (lane < 16)
            atomicMax((int*)&pool[batch * 256 + c], __float_as_int(mx));
    }
}

// ---------------- pool init (relu floor = 0) ----------------
__global__ __launch_bounds__(256) void pool_init(float* __restrict__ pool) {
    pool[blockIdx.x * 256 + threadIdx.x] = 0.0f;
}

// ---------------- head Dense(3), wave-parallel ----------------
__global__ __launch_bounds__(256) void head_kernel(const float* __restrict__ pool,
                                                   const float* __restrict__ wd,
                                                   const float* __restrict__ bd,
                                                   float* __restrict__ out) {
    const int b = blockIdx.x;
    const int t = threadIdx.x;
    const int w = t >> 6;
    const int lane = t & 63;
    if (w < 3) {
        float s = 0.f;
        #pragma unroll
        for (int k = 0; k < 256; k += 64)
            s += pool[b * 256 + k + lane] * wd[(k + lane) * 3 + w];
        #pragma unroll
        for (int off = 32; off; off >>= 1) s += __shfl_down(s, off);
        if (lane == 0) out[b * 3 + w] = s + bd[w];
    }
}

extern "C" void kernel_launch(void* const* d_in, const int* in_sizes, int n_in,
                              void* d_out, int out_size, void* d_ws, size_t ws_size,
                              hipStream_t stream) {
    const float* x   = (const float*)d_in[0];
    const float* a   = (const float*)d_in[1];
    const float* eps = (const float*)d_in[2];
    const float* w1  = (const float*)d_in[3];
    const float* b1  = (const float*)d_in[4];
    const float* g1  = (const float*)d_in[5];
    const float* be1 = (const float*)d_in[6];
    const float* m1  = (const float*)d_in[7];
    const float* v1  = (const float*)d_in[8];
    const float* w2  = (const float*)d_in[9];
    const float* b2  = (const float*)d_in[10];
    const float* g2  = (const float*)d_in[11];
    const float* be2 = (const float*)d_in[12];
    const float* m2  = (const float*)d_in[13];
    const float* v2  = (const float*)d_in[14];
    const float* w3  = (const float*)d_in[15];
    const float* b3  = (const float*)d_in[16];
    const float* g3  = (const float*)d_in[17];
    const float* be3 = (const float*)d_in[18];
    const float* m3  = (const float*)d_in[19];
    const float* v3  = (const float*)d_in[20];
    const float* wd  = (const float*)d_in[21];
    const float* bd  = (const float*)d_in[22];
    float* out = (float*)d_out;

    // Workspace: Xp @0 (16MB), Wp @16M (640KB), pool @17M (32KB). No h0.
    char* ws = (char*)d_ws;
    ushort* Xp   = (ushort*)(ws);
    ushort* Wp   = (ushort*)(ws + (16u << 20));
    float*  pool = (float*)(ws + (17u << 20));

    pool_init<<<32, 256, 0, stream>>>(pool);
    prep_w<<<640, 256, 0, stream>>>(w1, w2, w3, Wp);
    prep_x<<<1024, 512, 0, stream>>>(x, Xp);
    mega_gin<<<512, 512, 0, stream>>>(x, a, Xp, Wp, eps,
        b1, g1, be1, m1, v1,
        b2, g2, be2, m2, v2,
        b3, g3, be3, m3, v3, pool);
    head_kernel<<<32, 256, 0, stream>>>(pool, wd, bd, out);
}